// Round 8
// baseline (181.118 us; speedup 1.0000x reference)
//
#include <hip/hip_runtime.h>

// Integrate-and-fire scan over time axis — fatter-thread variant (C=8).
// x: [T=32, N=4194304] fp32 -> spikes same shape.
//
// R7 (C=4, 1024 blocks): 181us = 94% of the 6.29 TB/s copy ceiling.
// This probes C=8 (512 blocks, ~8 waves/CU): each wave reads a dense
// 8 KiB burst per time step (8 contiguous-1KiB dwordx4 loads), each
// block walks a contiguous 32 KiB window per t-slice. Continuing the
// "fewer, denser waves -> better DRAM row locality" trend that bought
// +24% in R7.
//
// Cache policy NT/NT — measured best (R3/R6 matrix): zero reuse inside
// a replay, bypass L2 allocation on both streams.

#define T_STEPS 32
#define C 8  // float4 columns per thread

typedef float f32x4 __attribute__((ext_vector_type(4)));

__global__ __launch_bounds__(256) void if_scan_kernel(
    const f32x4* __restrict__ x, f32x4* __restrict__ out, int nvec) {
    const int tid = threadIdx.x;
    const int blk = blockIdx.x;

    // thread's k-th column: blk*2048 + k*256 + tid (chunks 4KiB apart,
    // lanes contiguous within each chunk -> fully coalesced b128)
    const int base = blk * (256 * C) + tid;

    float m[C][4];
#pragma unroll
    for (int k = 0; k < C; ++k)
        m[k][0] = m[k][1] = m[k][2] = m[k][3] = 0.f;

#pragma unroll 2
    for (int t = 0; t < T_STEPS; ++t) {
        const size_t row = (size_t)t * nvec;

        f32x4 xt[C];
#pragma unroll
        for (int k = 0; k < C; ++k)
            xt[k] = __builtin_nontemporal_load(&x[row + base + k * 256]);

        f32x4 s[C];
#pragma unroll
        for (int k = 0; k < C; ++k) {
            m[k][0] += xt[k].x; s[k].x = (m[k][0] >= 1.0f) ? 1.0f : 0.0f; m[k][0] = (s[k].x != 0.0f) ? 0.0f : m[k][0];
            m[k][1] += xt[k].y; s[k].y = (m[k][1] >= 1.0f) ? 1.0f : 0.0f; m[k][1] = (s[k].y != 0.0f) ? 0.0f : m[k][1];
            m[k][2] += xt[k].z; s[k].z = (m[k][2] >= 1.0f) ? 1.0f : 0.0f; m[k][2] = (s[k].z != 0.0f) ? 0.0f : m[k][2];
            m[k][3] += xt[k].w; s[k].w = (m[k][3] >= 1.0f) ? 1.0f : 0.0f; m[k][3] = (s[k].w != 0.0f) ? 0.0f : m[k][3];
        }

#pragma unroll
        for (int k = 0; k < C; ++k)
            __builtin_nontemporal_store(s[k], &out[row + base + k * 256]);
    }
}

extern "C" void kernel_launch(void* const* d_in, const int* in_sizes, int n_in,
                              void* d_out, int out_size, void* d_ws, size_t ws_size,
                              hipStream_t stream) {
    const float* x = (const float*)d_in[0];
    float* out = (float*)d_out;

    const long long total = (long long)in_sizes[0];   // T*N = 134217728
    const int N = (int)(total / T_STEPS);             // 4194304 neurons
    const int nvec = N / 4;                           // 1048576 float4 columns

    const int block = 256;
    const int grid = nvec / (block * C);              // 512 blocks

    if_scan_kernel<<<grid, block, 0, stream>>>(
        (const f32x4*)x, (f32x4*)out, nvec);
}